// Round 3
// baseline (732.690 us; speedup 1.0000x reference)
//
#include <hip/hip_runtime.h>

// ---------------------------------------------------------------------------
// Problem constants
// ---------------------------------------------------------------------------
constexpr int B_  = 32;
constexpr int S_  = 4096;
constexpr int H_  = 128;
constexpr int DH_ = 128;
constexpr int R_  = 512;
constexpr int QR_ = 1536;
constexpr int N1  = H_ * DH_;  // 16384

typedef __attribute__((ext_vector_type(4))) float f32x4;
typedef __attribute__((ext_vector_type(8))) short bf16x8;
typedef __attribute__((ext_vector_type(2))) unsigned u32x2;

// fp32 -> bf16, round-to-nearest-even
__device__ inline short f2bf(float f) {
  unsigned u = __builtin_bit_cast(unsigned, f);
  unsigned r = u + 0x7FFFu + ((u >> 16) & 1u);
  return (short)(r >> 16);
}

__device__ inline bf16x8 cvt8(f32x4 a, f32x4 b) {
  bf16x8 r;
  r[0] = f2bf(a[0]); r[1] = f2bf(a[1]); r[2] = f2bf(a[2]); r[3] = f2bf(a[3]);
  r[4] = f2bf(b[0]); r[5] = f2bf(b[1]); r[6] = f2bf(b[2]); r[7] = f2bf(b[3]);
  return r;
}

// ---------------------------------------------------------------------------
// K1: q projection  q[b,n] = hsq[b,:] . wq[n,:] + bq[n]
// MFMA 16x16x32, A = hsq (M=32 b), B = wq (N=16 per wave). Both K-major in
// global memory -> direct fragment loads, no LDS. Output stored TRANSPOSED
// as q_t[n][b] (C-layout writes 4 consecutive b per lane -> dwordx4).
// grid 256 x block 256 (4 waves, one 16-wide n-tile each)
// ---------------------------------------------------------------------------
__global__ __launch_bounds__(256) void k1_qproj(
    const float* __restrict__ hsq, const float* __restrict__ wq,
    const float* __restrict__ bq, float* __restrict__ q_t) {
  const int lane = threadIdx.x & 63;
  const int wave = threadIdx.x >> 6;
  const int nt   = blockIdx.x * 4 + wave;   // 0..1023
  const int n0   = nt * 16;
  const int col  = lane & 15;
  const int ks   = (lane >> 4) * 8;

  f32x4 acc0 = {0.f, 0.f, 0.f, 0.f};
  f32x4 acc1 = {0.f, 0.f, 0.f, 0.f};
  const float* arow0 = hsq + (long)col * QR_;         // b = col
  const float* arow1 = hsq + (long)(col + 16) * QR_;  // b = col+16
  const float* brow  = wq + (long)(n0 + col) * QR_;   // n = n0+col

  for (int k0 = 0; k0 < QR_; k0 += 32) {
    const int k = k0 + ks;
    bf16x8 a0 = cvt8(*(const f32x4*)(arow0 + k), *(const f32x4*)(arow0 + k + 4));
    bf16x8 a1 = cvt8(*(const f32x4*)(arow1 + k), *(const f32x4*)(arow1 + k + 4));
    bf16x8 bb = cvt8(*(const f32x4*)(brow + k),  *(const f32x4*)(brow + k + 4));
    acc0 = __builtin_amdgcn_mfma_f32_16x16x32_bf16(a0, bb, acc0, 0, 0, 0);
    acc1 = __builtin_amdgcn_mfma_f32_16x16x32_bf16(a1, bb, acc1, 0, 0, 0);
  }
  // C layout (m89): col = lane&15 (n), row = (lane>>4)*4 + reg (b)
  const float bias = bq[n0 + col];
  const int rb = (lane >> 4) * 4;
  f32x4 o0 = acc0 + bias;
  f32x4 o1 = acc1 + bias;
  *(f32x4*)(q_t + (long)(n0 + col) * B_ + rb)      = o0;
  *(f32x4*)(q_t + (long)(n0 + col) * B_ + rb + 16) = o1;
}

// ---------------------------------------------------------------------------
// K2: k-absorb  q_abs[b,h,r] = sum_d q[b,h,d] * w_kc[h,d,r]   (bf16 out)
// VALU with q block staged in LDS as [d][b]. grid (2 r-halves, 128 h)
// ---------------------------------------------------------------------------
__global__ __launch_bounds__(256) void k2_absorb(
    const float* __restrict__ q_t, const float* __restrict__ w_kc,
    short* __restrict__ q_abs) {
  __shared__ float qs[DH_ * B_];  // [d][b], 16 KB
  const int h  = blockIdx.y;
  const int r0 = blockIdx.x * 256;
  const int t  = threadIdx.x;

  const float* src = q_t + (long)h * DH_ * B_;  // rows n=h*128+d, contiguous
  for (int i = t; i < DH_ * B_; i += 256) qs[i] = src[i];
  __syncthreads();

  const int r = r0 + t;
  const float* wrow = w_kc + (long)h * DH_ * R_ + r;  // stride R_ over d
  float acc[B_];
#pragma unroll
  for (int b = 0; b < B_; b++) acc[b] = 0.f;

#pragma unroll 2
  for (int d = 0; d < DH_; d++) {
    const float wv = wrow[(long)d * R_];
    const float* ql = qs + d * B_;
#pragma unroll
    for (int b4 = 0; b4 < B_; b4 += 4) {
      f32x4 q4 = *(const f32x4*)(ql + b4);
      acc[b4 + 0] += wv * q4[0];
      acc[b4 + 1] += wv * q4[1];
      acc[b4 + 2] += wv * q4[2];
      acc[b4 + 3] += wv * q4[3];
    }
  }
#pragma unroll
  for (int b = 0; b < B_; b++)
    q_abs[((long)b * H_ + h) * R_ + r] = f2bf(acc[b]);
}

// ---------------------------------------------------------------------------
// K3: attention scores  scores[b,h,s] = q_abs[b,h,:] . kv[b,s,:]
// MFMA per wave: M=128 (all heads, 8 frags) x N=32 s (2 frags), K=512.
// A (q_abs bf16) and B (kv fp32->bf16) are both K(r)-major -> direct loads.
// grid (32 s-groups, 32 b) x 256 (4 waves => 32-wide s-tile per wave)
// ---------------------------------------------------------------------------
__global__ __launch_bounds__(256) void k3_scores(
    const short* __restrict__ q_abs, const float* __restrict__ kv,
    float* __restrict__ scores) {
  const int lane = threadIdx.x & 63;
  const int wave = threadIdx.x >> 6;
  const int b    = blockIdx.y;
  const int s0   = (blockIdx.x * 4 + wave) * 32;
  const int col  = lane & 15;
  const int ks   = (lane >> 4) * 8;

  f32x4 acc[8][2];
#pragma unroll
  for (int i = 0; i < 8; i++) {
    acc[i][0] = (f32x4){0.f, 0.f, 0.f, 0.f};
    acc[i][1] = (f32x4){0.f, 0.f, 0.f, 0.f};
  }

  const short* abase = q_abs + ((long)b * H_ + col) * R_;       // + mf*16*R_
  const float* b0row = kv + ((long)b * S_ + s0 + col) * R_;     // n-frag 0
  const float* b1row = b0row + (long)16 * R_;                   // n-frag 1

  for (int k0 = 0; k0 < R_; k0 += 32) {
    const int k = k0 + ks;
    bf16x8 bf0 = cvt8(*(const f32x4*)(b0row + k), *(const f32x4*)(b0row + k + 4));
    bf16x8 bf1 = cvt8(*(const f32x4*)(b1row + k), *(const f32x4*)(b1row + k + 4));
#pragma unroll
    for (int mf = 0; mf < 8; mf++) {
      bf16x8 af = *(const bf16x8*)(abase + (long)mf * 16 * R_ + k);
      acc[mf][0] = __builtin_amdgcn_mfma_f32_16x16x32_bf16(af, bf0, acc[mf][0], 0, 0, 0);
      acc[mf][1] = __builtin_amdgcn_mfma_f32_16x16x32_bf16(af, bf1, acc[mf][1], 0, 0, 0);
    }
  }

  const int rowb = (lane >> 4) * 4;
#pragma unroll
  for (int mf = 0; mf < 8; mf++)
#pragma unroll
    for (int nf = 0; nf < 2; nf++)
#pragma unroll
      for (int rg = 0; rg < 4; rg++) {
        const int hh = mf * 16 + rowb + rg;
        const int ss = s0 + nf * 16 + col;
        scores[((long)b * H_ + hh) * S_ + ss] = acc[mf][nf][rg];
      }
}

// ---------------------------------------------------------------------------
// K4: row softmax (fp32) -> P bf16.  grid (128 h, 32 b) x 256
// ---------------------------------------------------------------------------
__global__ __launch_bounds__(256) void k4_softmax(
    const float* __restrict__ scores, short* __restrict__ P) {
  const int h = blockIdx.x, b = blockIdx.y;
  const long base = ((long)b * H_ + h) * S_;
  const float* row = scores + base;
  short* prow = P + base;
  const int t = threadIdx.x;

  f32x4 v[4];
  float mx = -3.4e38f;
#pragma unroll
  for (int i = 0; i < 4; i++) {
    v[i] = *(const f32x4*)(row + i * 1024 + t * 4);
    mx = fmaxf(mx, fmaxf(fmaxf(v[i][0], v[i][1]), fmaxf(v[i][2], v[i][3])));
  }
#pragma unroll
  for (int off = 32; off > 0; off >>= 1) mx = fmaxf(mx, __shfl_xor(mx, off));

  __shared__ float redm[4], reds[4];
  const int wave = t >> 6;
  if ((t & 63) == 0) redm[wave] = mx;
  __syncthreads();
  mx = fmaxf(fmaxf(redm[0], redm[1]), fmaxf(redm[2], redm[3]));

  float sum = 0.f;
#pragma unroll
  for (int i = 0; i < 4; i++)
#pragma unroll
    for (int j = 0; j < 4; j++) {
      const float e = exp2f((v[i][j] - mx) * 1.44269504089f);
      v[i][j] = e;
      sum += e;
    }
#pragma unroll
  for (int off = 32; off > 0; off >>= 1) sum += __shfl_xor(sum, off);
  if ((t & 63) == 0) reds[wave] = sum;
  __syncthreads();
  sum = (reds[0] + reds[1]) + (reds[2] + reds[3]);
  const float inv = 1.f / sum;

#pragma unroll
  for (int i = 0; i < 4; i++) {
    const unsigned p0 = (unsigned)(unsigned short)f2bf(v[i][0] * inv) |
                        ((unsigned)(unsigned short)f2bf(v[i][1] * inv) << 16);
    const unsigned p1 = (unsigned)(unsigned short)f2bf(v[i][2] * inv) |
                        ((unsigned)(unsigned short)f2bf(v[i][3] * inv) << 16);
    u32x2 pk = {p0, p1};
    *(u32x2*)(prow + i * 1024 + t * 4) = pk;
  }
}

// ---------------------------------------------------------------------------
// K5: context partials  ctxp[ck][b][h][r] = sum_{s in chunk} P[b,h,s]*kv[b,s,r]
// MFMA: M=128 h (8 frags) x N=32 r (2 frags), K = 1024-s chunk.
// A (P bf16) K(s)-major -> direct. B (kv) is N(r)-major -> per-lane global
// gather: lane reads kv[s0+(lane>>4)*8+j][r0+(lane&15)] (4 x 64B segments).
// grid (16, 32 b) x 256; wave id -> (r-tile 0..15, k-chunk 0..3)
// NOTE: ctxp ALIASES the scores buffer (scores is dead after K4).
// ---------------------------------------------------------------------------
__global__ __launch_bounds__(256) void k5_context(
    const short* __restrict__ P, const float* __restrict__ kv,
    float* __restrict__ ctxp) {
  const int lane = threadIdx.x & 63;
  const int wave = threadIdx.x >> 6;
  const int b    = blockIdx.y;
  const int id   = blockIdx.x * 4 + wave;  // 0..63
  const int rt   = id & 15;
  const int ck   = id >> 4;
  const int r0   = rt * 32;
  const int s0   = ck * 1024;
  const int col  = lane & 15;
  const int ks   = (lane >> 4) * 8;

  f32x4 acc[8][2];
#pragma unroll
  for (int i = 0; i < 8; i++) {
    acc[i][0] = (f32x4){0.f, 0.f, 0.f, 0.f};
    acc[i][1] = (f32x4){0.f, 0.f, 0.f, 0.f};
  }

  const short* abase = P + ((long)b * H_ + col) * S_;  // + mf*16*S_
  const float* kvb   = kv + (long)b * S_ * R_;

  for (int k0 = 0; k0 < 1024; k0 += 32) {
    const int s = s0 + k0 + ks;
    float bv0[8], bv1[8];
#pragma unroll
    for (int j = 0; j < 8; j++) {
      const float* kr = kvb + (long)(s + j) * R_ + r0 + col;
      bv0[j] = kr[0];
      bv1[j] = kr[16];
    }
    f32x4 lo0 = {bv0[0], bv0[1], bv0[2], bv0[3]};
    f32x4 hi0 = {bv0[4], bv0[5], bv0[6], bv0[7]};
    f32x4 lo1 = {bv1[0], bv1[1], bv1[2], bv1[3]};
    f32x4 hi1 = {bv1[4], bv1[5], bv1[6], bv1[7]};
    bf16x8 bf0 = cvt8(lo0, hi0);
    bf16x8 bf1 = cvt8(lo1, hi1);
#pragma unroll
    for (int mf = 0; mf < 8; mf++) {
      bf16x8 af = *(const bf16x8*)(abase + (long)mf * 16 * S_ + s);
      acc[mf][0] = __builtin_amdgcn_mfma_f32_16x16x32_bf16(af, bf0, acc[mf][0], 0, 0, 0);
      acc[mf][1] = __builtin_amdgcn_mfma_f32_16x16x32_bf16(af, bf1, acc[mf][1], 0, 0, 0);
    }
  }

  const int rowb = (lane >> 4) * 4;
  float* obase = ctxp + ((long)ck * B_ + b) * H_ * R_;
#pragma unroll
  for (int mf = 0; mf < 8; mf++)
#pragma unroll
    for (int nf = 0; nf < 2; nf++)
#pragma unroll
      for (int rg = 0; rg < 4; rg++) {
        const int hh = mf * 16 + rowb + rg;
        const int rr = r0 + nf * 16 + col;
        obase[(long)hh * R_ + rr] = acc[mf][nf][rg];
      }
}

// ---------------------------------------------------------------------------
// K6: v-absorb + partial reduce
//   out[b, h*DH+d] = sum_r w_vc[h,d,r] * (sum_ck ctxp[ck][b][h][r])
// VALU; summed context staged in LDS [b][r] (64 KB). grid 128 (h) x 256
// ---------------------------------------------------------------------------
__global__ __launch_bounds__(256) void k6_out(
    const float* __restrict__ ctxp, const float* __restrict__ w_vc,
    float* __restrict__ out) {
  __shared__ float cs[B_ * R_];  // [b][r]
  const int h = blockIdx.x;
  const int t = threadIdx.x;
  const long pstride = (long)B_ * H_ * R_;

  for (int i = t; i < B_ * R_; i += 256) {
    const int b = i >> 9;
    const int r = i & 511;
    const long base = ((long)b * H_ + h) * R_ + r;
    cs[i] = ctxp[base] + ctxp[base + pstride] +
            ctxp[base + 2 * pstride] + ctxp[base + 3 * pstride];
  }
  __syncthreads();

  const int d  = t >> 1;
  const int bh = (t & 1) * 16;
  const float* wrow = w_vc + ((long)h * DH_ + d) * R_;

  float acc[16];
#pragma unroll
  for (int b = 0; b < 16; b++) acc[b] = 0.f;

  for (int r = 0; r < R_; r += 4) {
    f32x4 w4 = *(const f32x4*)(wrow + r);
#pragma unroll
    for (int b = 0; b < 16; b++) {
      f32x4 c4 = *(const f32x4*)(cs + (bh + b) * R_ + r);
      acc[b] += w4[0] * c4[0] + w4[1] * c4[1] + w4[2] * c4[2] + w4[3] * c4[3];
    }
  }
#pragma unroll
  for (int b = 0; b < 16; b++)
    out[(long)(bh + b) * N1 + h * DH_ + d] = acc[b];
}

// ---------------------------------------------------------------------------
// launch
//
// ws budget: round-2 used 140.5 MB and corrupted a neighboring allocation
// (pristine input copies) -> replays diverged. Fix: ctxp ALIASES scores
// (scores dead after k4; k5 reads only P and kv). Total ws = 102 MiB.
// ---------------------------------------------------------------------------
extern "C" void kernel_launch(void* const* d_in, const int* in_sizes, int n_in,
                              void* d_out, int out_size, void* d_ws, size_t ws_size,
                              hipStream_t stream) {
  (void)in_sizes; (void)n_in; (void)out_size; (void)ws_size;
  const float* hsq = (const float*)d_in[0];  // [B, QR]
  const float* kv  = (const float*)d_in[1];  // [B, S, R]
  const float* wq  = (const float*)d_in[2];  // [H*DH, QR]
  const float* bq  = (const float*)d_in[3];  // [H*DH]
  const float* wkc = (const float*)d_in[4];  // [H, DH, R]
  const float* wvc = (const float*)d_in[5];  // [H, DH, R]
  float* out = (float*)d_out;                // [B, H*DH]

  char* ws = (char*)d_ws;
  float* q_t    = (float*)(ws);               //  [0,       2.10 MB)  [N1][B] fp32
  short* q_abs  = (short*)(ws + 2097152);     //  [2.10,    6.29 MB)  [B][H][R] bf16
  float* scores = (float*)(ws + 6291456);     //  [6.29,   73.40 MB)  [B][H][S] fp32
  float* ctxp   = (float*)(ws + 6291456);     //  ALIAS of scores: [4][B][H][R] fp32 (33.6 MB)
  short* P      = (short*)(ws + 73400320);    //  [73.40, 106.95 MB)  [B][H][S] bf16
                                              //  total 102 MiB

  k1_qproj  <<<256, 256, 0, stream>>>(hsq, wq, bq, q_t);
  k2_absorb <<<dim3(2, 128), 256, 0, stream>>>(q_t, wkc, q_abs);
  k3_scores <<<dim3(32, 32), 256, 0, stream>>>(q_abs, kv, scores);
  k4_softmax<<<dim3(128, 32), 256, 0, stream>>>(scores, P);
  k5_context<<<dim3(16, 32), 256, 0, stream>>>(P, kv, ctxp);
  k6_out    <<<128, 256, 0, stream>>>(ctxp, wvc, out);
}